// Round 12
// baseline (77.509 us; speedup 1.0000x reference)
//
#include <hip/hip_runtime.h>
#include <hip/hip_bf16.h>
#include <math.h>

#define BB 64
#define SS 512
#define DD 1024
#define LL 9
#define NCHUNK 32
#define CLEN 16
#define KH 512     // k-half per block
#define WSTR2 516  // padded LDS stride for the 512-wide W half

#define DPP_ADD(v, ctrl)                                                     \
  v += __int_as_float(__builtin_amdgcn_update_dpp(                           \
      0, __float_as_int(v), ctrl, 0xF, 0xF, false))

template <int R>
__device__ inline float swz(float x) {
  return __int_as_float(
      __builtin_amdgcn_ds_swizzle(__float_as_int(x), (R << 10) | 0x1F));
}

// ---------------- GEMM, k-split: logits[r][l] = sum_k in[r][k]W[k][l] + b[l]
// 2048 blocks x 128 thr. Block = (32 rows) x (one k-half of 512). LDS = half
// of W = 18KB -> 8 blocks/CU resident WITH backfill (the r10 probe regime:
// 16 waves/CU, 64KB/CU reads in flight). Per-wave structure byte-equivalent
// to r4: 16 rows as 4 quads, p=lane&15 k-split, 1-deep prefetch, DPP reduce.
// Two k-half blocks combine via atomicAdd (exactly 2 addends -> bitwise
// deterministic); bias added by khalf==0; logits pre-zeroed by memset.
__global__ __launch_bounds__(128) void gemm_kernel(
    const float* __restrict__ in, const float* __restrict__ W,
    const float* __restrict__ bias, float* __restrict__ out) {
  __shared__ float Wt[LL * WSTR2];  // 18.1 KB
  int tid = threadIdx.x;
  int bid = blockIdx.x;
  int rowblk = bid >> 1;
  int khalf = bid & 1;

  // stage this k-half of W: global reads contiguous, LDS writes once/block
  for (int i = tid; i < KH * LL; i += 128) {
    int k = i / LL, l = i - k * LL;  // W row-major [k][l]
    Wt[l * WSTR2 + k] = W[khalf * (KH * LL) + i];
  }
  __syncthreads();

  int lane = tid & 63;
  int wave = tid >> 6;  // 0..1
  int p = lane & 15;
  int sub = lane >> 4;

  int r0 = rowblk * 32 + wave * 16 + sub;  // rows r0 + 4q, q=0..3
  const float* x0 = in + (size_t)r0 * DD + khalf * KH + p * 4;

  float acc[4][LL];
#pragma unroll
  for (int q = 0; q < 4; ++q)
#pragma unroll
    for (int l = 0; l < LL; ++l) acc[q][l] = 0.f;

  float4 a[4], an[4];
#pragma unroll
  for (int q = 0; q < 4; ++q)
    a[q] = *reinterpret_cast<const float4*>(x0 + (size_t)q * 4 * DD);

  for (int it = 0; it < 8; ++it) {  // 8 x 64 floats = 512 (this k-half)
    if (it < 7) {
#pragma unroll
      for (int q = 0; q < 4; ++q)
        an[q] = *reinterpret_cast<const float4*>(x0 + (size_t)q * 4 * DD +
                                                 (it + 1) * 64);
    }
    int k0 = it * 64 + p * 4;
    float4 w4[LL];
#pragma unroll
    for (int l = 0; l < LL; ++l)
      w4[l] = *reinterpret_cast<const float4*>(&Wt[l * WSTR2 + k0]);
#pragma unroll
    for (int q = 0; q < 4; ++q)
#pragma unroll
      for (int l = 0; l < LL; ++l)
        acc[q][l] += a[q].x * w4[l].x + a[q].y * w4[l].y + a[q].z * w4[l].z +
                     a[q].w * w4[l].w;
    if (it < 7) {
#pragma unroll
      for (int q = 0; q < 4; ++q) a[q] = an[q];
    }
  }

#pragma unroll
  for (int q = 0; q < 4; ++q)
#pragma unroll
    for (int l = 0; l < LL; ++l) {
      DPP_ADD(acc[q][l], 0x111);
      DPP_ADD(acc[q][l], 0x112);
      DPP_ADD(acc[q][l], 0x114);
      DPP_ADD(acc[q][l], 0x118);
    }
  if (p == 15) {
#pragma unroll
    for (int q = 0; q < 4; ++q)
#pragma unroll
      for (int l = 0; l < LL; ++l) {
        float v = acc[q][l] + (khalf == 0 ? bias[l] : 0.f);
        atomicAdd(&out[(size_t)(r0 + q * 4) * LL + l], v);
      }
  }
}

// ---------------- Phase 1: per-(batch,chunk) 16-step transfer matrix +
// per-chunk numerator partial (r4 form, byte-identical).
__global__ __launch_bounds__(64) void crf_chunk_kernel(
    const float* __restrict__ logits, const int* __restrict__ targets,
    const int* __restrict__ seqlen, const float* __restrict__ trans,
    float* __restrict__ mats, float* __restrict__ scales,
    float* __restrict__ numpart, unsigned* __restrict__ counter) {
  if (blockIdx.x == 0 && threadIdx.x == 0) *counter = 0u;

  int lane = threadIdx.x;
  int j = lane & 15;
  int gid = blockIdx.x * 4 + (lane >> 4);
  int b = gid >> 5;
  int k = gid & 31;
  int len = seqlen[b];

  float Mx[81];
#pragma unroll
  for (int i = 0; i < 81; ++i) Mx[i] = __expf(trans[i]);

  float T[LL];
#pragma unroll
  for (int c = 0; c < LL; ++c) T[c] = (j == c) ? 1.f : 0.f;
  float Cl = 0.f;

  const float* lb = logits + (size_t)b * SS * LL;
  const int* tb = targets + (size_t)b * SS;
  int t0 = k * CLEN + 1;
  int tend = (t0 + CLEN < SS) ? (t0 + CLEN) : SS;

  float e[LL];
#pragma unroll
  for (int c = 0; c < LL; ++c) e[c] = lb[t0 * LL + c];

  for (int t = t0; t < tend; ++t) {
    float Ex[LL];
#pragma unroll
    for (int c = 0; c < LL; ++c) Ex[c] = __expf(e[c]);
    if (t + 1 < tend) {
#pragma unroll
      for (int c = 0; c < LL; ++c) e[c] = lb[(t + 1) * LL + c];
    }
    bool active = (t < len);
    float nT[LL];
#pragma unroll
    for (int c = 0; c < LL; ++c) {
      float s = 0.f;
#pragma unroll
      for (int m = 0; m < LL; ++m) s += T[m] * Mx[m * LL + c];
      nT[c] = s * Ex[c];
    }
#pragma unroll
    for (int c = 0; c < LL; ++c) T[c] = active ? nT[c] : T[c];

    if (((t - t0) & 7) == 7) {
      float m = T[0];
#pragma unroll
      for (int c = 1; c < LL; ++c) m = fmaxf(m, T[c]);
      m = fmaxf(m, swz<1>(m));
      m = fmaxf(m, swz<2>(m));
      m = fmaxf(m, swz<4>(m));
      m = fmaxf(m, swz<8>(m));
      float inv = 1.f / m;
#pragma unroll
      for (int c = 0; c < LL; ++c) T[c] *= inv;
      Cl += __logf(m);
    }
  }
  {
    float m = T[0];
#pragma unroll
    for (int c = 1; c < LL; ++c) m = fmaxf(m, T[c]);
    m = fmaxf(m, swz<1>(m));
    m = fmaxf(m, swz<2>(m));
    m = fmaxf(m, swz<4>(m));
    m = fmaxf(m, swz<8>(m));
    float inv = 1.f / m;
#pragma unroll
    for (int c = 0; c < LL; ++c) T[c] *= inv;
    Cl += __logf(m);
  }

  float* Mg = mats + (size_t)gid * 256;
#pragma unroll
  for (int c = 0; c < 16; ++c)
    Mg[c * 16 + (j ^ c)] = (c < LL) ? T[c] : 0.f;
  if (j == 0) scales[gid] = Cl;

  int t = t0 + j;
  float np = 0.f;
  if (t < tend && t < len) {
    int tg = tb[t];
    np = lb[t * LL + tg] + trans[tb[t - 1] * LL + tg];
  }
  np += swz<1>(np);
  np += swz<2>(np);
  np += swz<4>(np);
  np += swz<8>(np);
  if (j == 0) numpart[gid] = np;
}

// ---------------- Phase 2: per-batch combine + deterministic final reduce
// (r4 form, byte-identical).
__global__ __launch_bounds__(64) void crf_combine_kernel(
    const float* __restrict__ logits, const int* __restrict__ targets,
    const float* __restrict__ mats, const float* __restrict__ scales,
    const float* __restrict__ numpart, float* __restrict__ partials,
    unsigned* __restrict__ counter, float* __restrict__ out_val) {
  int lane = threadIdx.x;
  int j = lane & 15;
  int b = blockIdx.x;
  const float* lb = logits + (size_t)b * SS * LL;
  const float* Mb = mats + (size_t)b * NCHUNK * 256;

  float extra = (lane < NCHUNK) ? scales[b * NCHUNK + lane]
                                : -numpart[b * NCHUNK + (lane - 32)];
  extra += __shfl_xor(extra, 1, 64);
  extra += __shfl_xor(extra, 2, 64);
  extra += __shfl_xor(extra, 4, 64);
  extra += __shfl_xor(extra, 8, 64);
  extra += __shfl_xor(extra, 16, 64);
  extra += __shfl_xor(extra, 32, 64);
  float emit0 = lb[targets[(size_t)b * SS]];

  float alpha = (j < LL) ? __expf(lb[j]) : 0.f;
  float C = 0.f;

  float4 c0 = *reinterpret_cast<const float4*>(Mb + j * 16 + 0);
  float4 c1 = *reinterpret_cast<const float4*>(Mb + j * 16 + 4);
  float4 c2 = *reinterpret_cast<const float4*>(Mb + j * 16 + 8);
  float4 c3 = *reinterpret_cast<const float4*>(Mb + j * 16 + 12);

  for (int k = 0; k < NCHUNK; ++k) {
    float4 n0, n1, n2, n3;
    if (k + 1 < NCHUNK) {
      const float* Mn = Mb + (size_t)(k + 1) * 256 + j * 16;
      n0 = *reinterpret_cast<const float4*>(Mn + 0);
      n1 = *reinterpret_cast<const float4*>(Mn + 4);
      n2 = *reinterpret_cast<const float4*>(Mn + 8);
      n3 = *reinterpret_cast<const float4*>(Mn + 12);
    }
    float s01 = alpha * c0.x + swz<1>(alpha) * c0.y;
    float s23 = swz<2>(alpha) * c0.z + swz<3>(alpha) * c0.w;
    float s45 = swz<4>(alpha) * c1.x + swz<5>(alpha) * c1.y;
    float s67 = swz<6>(alpha) * c1.z + swz<7>(alpha) * c1.w;
    float s89 = swz<8>(alpha) * c2.x + swz<9>(alpha) * c2.y;
    float sab = swz<10>(alpha) * c2.z + swz<11>(alpha) * c2.w;
    float scd = swz<12>(alpha) * c3.x + swz<13>(alpha) * c3.y;
    float sef = swz<14>(alpha) * c3.z + swz<15>(alpha) * c3.w;
    alpha = ((s01 + s23) + (s45 + s67)) + ((s89 + sab) + (scd + sef));

    if ((k & 3) == 3) {  // renorm every 4 chunks (growth <= 9^4, safe)
      float m = alpha;
      m = fmaxf(m, swz<1>(m));
      m = fmaxf(m, swz<2>(m));
      m = fmaxf(m, swz<4>(m));
      m = fmaxf(m, swz<8>(m));
      float inv = 1.f / m;
      alpha *= inv;
      C += __logf(m);
    }
    if (k + 1 < NCHUNK) { c0 = n0; c1 = n1; c2 = n2; c3 = n3; }
  }

  float s = alpha;
  s += swz<1>(s);
  s += swz<2>(s);
  s += swz<4>(s);
  s += swz<8>(s);
  float result = extra + C + __logf(s) - emit0;

  if (lane == 0) partials[b] = result;
  __threadfence();
  unsigned old = 0;
  if (lane == 0) old = atomicAdd(counter, 1u);
  old = __shfl(old, 0, 64);
  if (old == BB - 1) {
    __threadfence();
    float v = partials[lane];
    v += __shfl_xor(v, 1, 64);
    v += __shfl_xor(v, 2, 64);
    v += __shfl_xor(v, 4, 64);
    v += __shfl_xor(v, 8, 64);
    v += __shfl_xor(v, 16, 64);
    v += __shfl_xor(v, 32, 64);
    if (lane == 0) {
      out_val[0] = v;
      *counter = 0u;
    }
  }
}

extern "C" void kernel_launch(void* const* d_in, const int* in_sizes, int n_in,
                              void* d_out, int out_size, void* d_ws,
                              size_t ws_size, hipStream_t stream) {
  const float* inputs = (const float*)d_in[0];
  const int* targets = (const int*)d_in[1];
  const int* seqlen = (const int*)d_in[2];
  const float* W = (const float*)d_in[4];
  const float* bias = (const float*)d_in[5];
  const float* trans = (const float*)d_in[6];
  float* out = (float*)d_out;

  float* mats = (float*)d_ws;                        // 64*32*256 f = 2 MB
  float* scales = mats + (size_t)BB * NCHUNK * 256;  // 2048 f
  float* numpart = scales + (size_t)BB * NCHUNK;     // 2048 f
  float* partials = numpart + (size_t)BB * NCHUNK;   // 64 f
  unsigned* counter = (unsigned*)(partials + BB);    // 1 u32

  // zero logits (atomic accumulation target), then k-split GEMM
  hipMemsetAsync(out + 1, 0, (size_t)BB * SS * LL * sizeof(float), stream);
  gemm_kernel<<<2048, 128, 0, stream>>>(inputs, W, bias, out + 1);
  crf_chunk_kernel<<<BB * NCHUNK / 4, 64, 0, stream>>>(
      out + 1, targets, seqlen, trans, mats, scales, numpart, counter);
  crf_combine_kernel<<<BB, 64, 0, stream>>>(out + 1, targets, mats, scales,
                                            numpart, partials, counter, out);
}

// Round 13
// 59.019 us; speedup vs baseline: 1.3133x; 1.3133x over previous
//
#include <hip/hip_runtime.h>
#include <hip/hip_bf16.h>
#include <math.h>

#define BB 64
#define SS 512
#define DD 1024
#define LL 9
#define NCHUNK 32
#define CLEN 16

#define DPP_ADD(v, ctrl)                                                     \
  v += __int_as_float(__builtin_amdgcn_update_dpp(                           \
      0, __float_as_int(v), ctrl, 0xF, 0xF, false))

typedef float v4f __attribute__((ext_vector_type(4)));

// nontemporal float4 load: emits global_load_dwordx4 with nt policy
// (compiler still tracks the result and inserts waitcnt).
__device__ inline v4f ldnt(const float* p) {
  return __builtin_nontemporal_load(reinterpret_cast<const v4f*>(p));
}

template <int R>
__device__ inline float swz(float x) {
  return __int_as_float(
      __builtin_amdgcn_ds_swizzle(__float_as_int(x), (R << 10) | 0x1F));
}

// ---------------- GEMM: logits[row][l] = sum_k in[row][k]*W[k][l] + b[l]
// Best-known structure (53.5us total): 512 blocks x 256 thr, wave = 16 rows
// (4 subs x 4 quads), p=lane&15 k-split, W in LDS, 1-deep prefetch, DPP
// reduce. SINGLE CHANGE vs that baseline: input loads are NONTEMPORAL so
// the 128 MiB zero-reuse stream doesn't thrash the 4 MiB/XCD L2.
__global__ __launch_bounds__(256) void gemm_kernel(
    const float* __restrict__ in, const float* __restrict__ W,
    const float* __restrict__ bias, float* __restrict__ out) {
  __shared__ float Wt[LL][DD];  // 36 KB
  int tid = threadIdx.x;
  for (int i = tid; i < DD * LL; i += 256) {
    int k = i / LL, l = i - k * LL;  // W row-major [k][l]
    Wt[l][k] = W[i];
  }
  __syncthreads();

  int lane = tid & 63;
  int wave = tid >> 6;
  int p = lane & 15;
  int sub = lane >> 4;

  int r0 = blockIdx.x * 64 + wave * 16 + sub;  // rows r0 + 4q, q=0..3
  const float* x0 = in + (size_t)r0 * DD + p * 4;

  float acc[4][LL];
#pragma unroll
  for (int q = 0; q < 4; ++q)
#pragma unroll
    for (int l = 0; l < LL; ++l) acc[q][l] = 0.f;

  v4f a[4], an[4];
#pragma unroll
  for (int q = 0; q < 4; ++q) a[q] = ldnt(x0 + (size_t)q * 4 * DD);

  for (int it = 0; it < 16; ++it) {
    if (it < 15) {
#pragma unroll
      for (int q = 0; q < 4; ++q)
        an[q] = ldnt(x0 + (size_t)q * 4 * DD + (it + 1) * 64);
    }
    int k0 = it * 64 + p * 4;
    float4 w4[LL];
#pragma unroll
    for (int l = 0; l < LL; ++l)
      w4[l] = *reinterpret_cast<const float4*>(&Wt[l][k0]);
#pragma unroll
    for (int q = 0; q < 4; ++q)
#pragma unroll
      for (int l = 0; l < LL; ++l)
        acc[q][l] += a[q].x * w4[l].x + a[q].y * w4[l].y + a[q].z * w4[l].z +
                     a[q].w * w4[l].w;
    if (it < 15) {
#pragma unroll
      for (int q = 0; q < 4; ++q) a[q] = an[q];
    }
  }

#pragma unroll
  for (int q = 0; q < 4; ++q)
#pragma unroll
    for (int l = 0; l < LL; ++l) {
      DPP_ADD(acc[q][l], 0x111);
      DPP_ADD(acc[q][l], 0x112);
      DPP_ADD(acc[q][l], 0x114);
      DPP_ADD(acc[q][l], 0x118);
    }
  if (p == 15) {
#pragma unroll
    for (int q = 0; q < 4; ++q)
#pragma unroll
      for (int l = 0; l < LL; ++l)
        out[(size_t)(r0 + q * 4) * LL + l] = acc[q][l] + bias[l];
  }
}

// ---------------- Phase 1: per-(batch,chunk) 16-step transfer matrix +
// per-chunk numerator partial (byte-identical to the 53.5us baseline).
__global__ __launch_bounds__(64) void crf_chunk_kernel(
    const float* __restrict__ logits, const int* __restrict__ targets,
    const int* __restrict__ seqlen, const float* __restrict__ trans,
    float* __restrict__ mats, float* __restrict__ scales,
    float* __restrict__ numpart, unsigned* __restrict__ counter) {
  if (blockIdx.x == 0 && threadIdx.x == 0) *counter = 0u;

  int lane = threadIdx.x;
  int j = lane & 15;
  int gid = blockIdx.x * 4 + (lane >> 4);
  int b = gid >> 5;
  int k = gid & 31;
  int len = seqlen[b];

  float Mx[81];
#pragma unroll
  for (int i = 0; i < 81; ++i) Mx[i] = __expf(trans[i]);

  float T[LL];
#pragma unroll
  for (int c = 0; c < LL; ++c) T[c] = (j == c) ? 1.f : 0.f;
  float Cl = 0.f;

  const float* lb = logits + (size_t)b * SS * LL;
  const int* tb = targets + (size_t)b * SS;
  int t0 = k * CLEN + 1;
  int tend = (t0 + CLEN < SS) ? (t0 + CLEN) : SS;

  float e[LL];
#pragma unroll
  for (int c = 0; c < LL; ++c) e[c] = lb[t0 * LL + c];

  for (int t = t0; t < tend; ++t) {
    float Ex[LL];
#pragma unroll
    for (int c = 0; c < LL; ++c) Ex[c] = __expf(e[c]);
    if (t + 1 < tend) {
#pragma unroll
      for (int c = 0; c < LL; ++c) e[c] = lb[(t + 1) * LL + c];
    }
    bool active = (t < len);
    float nT[LL];
#pragma unroll
    for (int c = 0; c < LL; ++c) {
      float s = 0.f;
#pragma unroll
      for (int m = 0; m < LL; ++m) s += T[m] * Mx[m * LL + c];
      nT[c] = s * Ex[c];
    }
#pragma unroll
    for (int c = 0; c < LL; ++c) T[c] = active ? nT[c] : T[c];

    if (((t - t0) & 7) == 7) {
      float m = T[0];
#pragma unroll
      for (int c = 1; c < LL; ++c) m = fmaxf(m, T[c]);
      m = fmaxf(m, swz<1>(m));
      m = fmaxf(m, swz<2>(m));
      m = fmaxf(m, swz<4>(m));
      m = fmaxf(m, swz<8>(m));
      float inv = 1.f / m;
#pragma unroll
      for (int c = 0; c < LL; ++c) T[c] *= inv;
      Cl += __logf(m);
    }
  }
  {
    float m = T[0];
#pragma unroll
    for (int c = 1; c < LL; ++c) m = fmaxf(m, T[c]);
    m = fmaxf(m, swz<1>(m));
    m = fmaxf(m, swz<2>(m));
    m = fmaxf(m, swz<4>(m));
    m = fmaxf(m, swz<8>(m));
    float inv = 1.f / m;
#pragma unroll
    for (int c = 0; c < LL; ++c) T[c] *= inv;
    Cl += __logf(m);
  }

  float* Mg = mats + (size_t)gid * 256;
#pragma unroll
  for (int c = 0; c < 16; ++c)
    Mg[c * 16 + (j ^ c)] = (c < LL) ? T[c] : 0.f;
  if (j == 0) scales[gid] = Cl;

  int t = t0 + j;
  float np = 0.f;
  if (t < tend && t < len) {
    int tg = tb[t];
    np = lb[t * LL + tg] + trans[tb[t - 1] * LL + tg];
  }
  np += swz<1>(np);
  np += swz<2>(np);
  np += swz<4>(np);
  np += swz<8>(np);
  if (j == 0) numpart[gid] = np;
}

// ---------------- Phase 2: per-batch combine + deterministic final reduce
// (byte-identical to the 53.5us baseline).
__global__ __launch_bounds__(64) void crf_combine_kernel(
    const float* __restrict__ logits, const int* __restrict__ targets,
    const float* __restrict__ mats, const float* __restrict__ scales,
    const float* __restrict__ numpart, float* __restrict__ partials,
    unsigned* __restrict__ counter, float* __restrict__ out_val) {
  int lane = threadIdx.x;
  int j = lane & 15;
  int b = blockIdx.x;
  const float* lb = logits + (size_t)b * SS * LL;
  const float* Mb = mats + (size_t)b * NCHUNK * 256;

  float extra = (lane < NCHUNK) ? scales[b * NCHUNK + lane]
                                : -numpart[b * NCHUNK + (lane - 32)];
  extra += __shfl_xor(extra, 1, 64);
  extra += __shfl_xor(extra, 2, 64);
  extra += __shfl_xor(extra, 4, 64);
  extra += __shfl_xor(extra, 8, 64);
  extra += __shfl_xor(extra, 16, 64);
  extra += __shfl_xor(extra, 32, 64);
  float emit0 = lb[targets[(size_t)b * SS]];

  float alpha = (j < LL) ? __expf(lb[j]) : 0.f;
  float C = 0.f;

  float4 c0 = *reinterpret_cast<const float4*>(Mb + j * 16 + 0);
  float4 c1 = *reinterpret_cast<const float4*>(Mb + j * 16 + 4);
  float4 c2 = *reinterpret_cast<const float4*>(Mb + j * 16 + 8);
  float4 c3 = *reinterpret_cast<const float4*>(Mb + j * 16 + 12);

  for (int k = 0; k < NCHUNK; ++k) {
    float4 n0, n1, n2, n3;
    if (k + 1 < NCHUNK) {
      const float* Mn = Mb + (size_t)(k + 1) * 256 + j * 16;
      n0 = *reinterpret_cast<const float4*>(Mn + 0);
      n1 = *reinterpret_cast<const float4*>(Mn + 4);
      n2 = *reinterpret_cast<const float4*>(Mn + 8);
      n3 = *reinterpret_cast<const float4*>(Mn + 12);
    }
    float s01 = alpha * c0.x + swz<1>(alpha) * c0.y;
    float s23 = swz<2>(alpha) * c0.z + swz<3>(alpha) * c0.w;
    float s45 = swz<4>(alpha) * c1.x + swz<5>(alpha) * c1.y;
    float s67 = swz<6>(alpha) * c1.z + swz<7>(alpha) * c1.w;
    float s89 = swz<8>(alpha) * c2.x + swz<9>(alpha) * c2.y;
    float sab = swz<10>(alpha) * c2.z + swz<11>(alpha) * c2.w;
    float scd = swz<12>(alpha) * c3.x + swz<13>(alpha) * c3.y;
    float sef = swz<14>(alpha) * c3.z + swz<15>(alpha) * c3.w;
    alpha = ((s01 + s23) + (s45 + s67)) + ((s89 + sab) + (scd + sef));

    if ((k & 3) == 3) {  // renorm every 4 chunks (growth <= 9^4, safe)
      float m = alpha;
      m = fmaxf(m, swz<1>(m));
      m = fmaxf(m, swz<2>(m));
      m = fmaxf(m, swz<4>(m));
      m = fmaxf(m, swz<8>(m));
      float inv = 1.f / m;
      alpha *= inv;
      C += __logf(m);
    }
    if (k + 1 < NCHUNK) { c0 = n0; c1 = n1; c2 = n2; c3 = n3; }
  }

  float s = alpha;
  s += swz<1>(s);
  s += swz<2>(s);
  s += swz<4>(s);
  s += swz<8>(s);
  float result = extra + C + __logf(s) - emit0;

  if (lane == 0) partials[b] = result;
  __threadfence();
  unsigned old = 0;
  if (lane == 0) old = atomicAdd(counter, 1u);
  old = __shfl(old, 0, 64);
  if (old == BB - 1) {
    __threadfence();
    float v = partials[lane];
    v += __shfl_xor(v, 1, 64);
    v += __shfl_xor(v, 2, 64);
    v += __shfl_xor(v, 4, 64);
    v += __shfl_xor(v, 8, 64);
    v += __shfl_xor(v, 16, 64);
    v += __shfl_xor(v, 32, 64);
    if (lane == 0) {
      out_val[0] = v;
      *counter = 0u;
    }
  }
}

extern "C" void kernel_launch(void* const* d_in, const int* in_sizes, int n_in,
                              void* d_out, int out_size, void* d_ws,
                              size_t ws_size, hipStream_t stream) {
  const float* inputs = (const float*)d_in[0];
  const int* targets = (const int*)d_in[1];
  const int* seqlen = (const int*)d_in[2];
  const float* W = (const float*)d_in[4];
  const float* bias = (const float*)d_in[5];
  const float* trans = (const float*)d_in[6];
  float* out = (float*)d_out;

  float* mats = (float*)d_ws;                        // 64*32*256 f = 2 MB
  float* scales = mats + (size_t)BB * NCHUNK * 256;  // 2048 f
  float* numpart = scales + (size_t)BB * NCHUNK;     // 2048 f
  float* partials = numpart + (size_t)BB * NCHUNK;   // 64 f
  unsigned* counter = (unsigned*)(partials + BB);    // 1 u32

  gemm_kernel<<<512, 256, 0, stream>>>(inputs, W, bias, out + 1);
  crf_chunk_kernel<<<BB * NCHUNK / 4, 64, 0, stream>>>(
      out + 1, targets, seqlen, trans, mats, scales, numpart, counter);
  crf_combine_kernel<<<BB, 64, 0, stream>>>(out + 1, targets, mats, scales,
                                            numpart, partials, counter, out);
}